// Round 3
// baseline (244.173 us; speedup 1.0000x reference)
//
#include <hip/hip_runtime.h>

// out[b, c] = x[b, c] * diag[c]   for x:(8192, 4096) fp32, diag:(4096,) fp32.
// Memory-bound streaming kernel. Ideal traffic = 268.4 MB -> ~43 us at 6.3 TB/s.
//
// Round-3 change: REMOVE nontemporal hints (single-variable isolation).
// Round-2 (nt load/store + ILP-8 grid-stride) regressed the kernel ~1.33x
// (est. 57 -> 75 us). The harness fill kernels hit 6.6-6.8 TB/s with regular
// stores, so nt is not needed for the write ceiling and is the prime suspect.
// Everything else kept identical to round 2:
//  - 4096 blocks x 256 threads, 8 float4 per thread, fully unrolled.
//  - STRIDE (1,048,576 float4) % SIZE4 == 0 -> thread's diag column invariant
//    across iterations -> diag loaded once, reused 8x.

typedef float f32x4 __attribute__((ext_vector_type(4)));

#define SIZE4 1024                  // 4096 / 4 columns in float4 units
#define N4 8388608                  // 8192 * 4096 / 4 total float4
#define TPB 256
#define BLOCKS 4096
#define PER_THREAD 8                // N4 / (BLOCKS * TPB)
#define STRIDE (BLOCKS * TPB)       // 1,048,576; % SIZE4 == 0 -> column invariant

__global__ __launch_bounds__(TPB) void diag_scale_kernel(
    const f32x4* __restrict__ x,
    const f32x4* __restrict__ d,
    f32x4* __restrict__ out)
{
    const int tid = blockIdx.x * TPB + threadIdx.x;       // 0 .. STRIDE-1
    const f32x4 dv = d[tid & (SIZE4 - 1)];                // column fixed for all k

    #pragma unroll
    for (int k = 0; k < PER_THREAD; ++k) {
        const int i = tid + k * STRIDE;                   // exact cover of N4
        const f32x4 xv = x[i];                            // regular load
        const f32x4 r = xv * dv;                          // elementwise vector mul
        out[i] = r;                                       // regular store
    }
}

extern "C" void kernel_launch(void* const* d_in, const int* in_sizes, int n_in,
                              void* d_out, int out_size, void* d_ws, size_t ws_size,
                              hipStream_t stream)
{
    const f32x4* x = (const f32x4*)d_in[0];   // (8192, 4096) fp32
    const f32x4* d = (const f32x4*)d_in[1];   // (4096,) fp32
    f32x4* out = (f32x4*)d_out;               // (8192, 4096) fp32

    diag_scale_kernel<<<BLOCKS, TPB, 0, stream>>>(x, d, out);
}

// Round 4
// 228.864 us; speedup vs baseline: 1.0669x; 1.0669x over previous
//
#include <hip/hip_runtime.h>

// out[b, c] = x[b, c] * diag[c]   for x:(8192, 4096) fp32, diag:(4096,) fp32.
// Memory-bound streaming kernel. Ideal traffic = 268.4 MB -> ~43 us at 6.3 TB/s.
//
// Round-4 change: CONTIGUOUS block-chunked ILP (revert the 16MB grid-stride).
// Round-3 measured the 16MB-stride ILP-8 kernel directly: 94-100 us, ~2.8 TB/s
// effective. Diagnosis: a thread's 8 loads + 8 stores sit exactly 16 MB apart
// -> same L2 set (4 MiB/XCD, pow2 sets) -> 16 lines/thread thrash one set.
// Fills / m13 copy (6.3-6.7 TB/s) stream contiguously.
//
// New structure:
//  - Each block owns a CONTIGUOUS 2048-float4 chunk (32 KB = 2 matrix rows).
//  - Thread iteration stride = 256 float4 = 4 KB -> no set aliasing, block
//    footprint compact, consecutive blocks stream consecutive chunks.
//  - Chunk base % 1024 == 0, so column(k) = (k&3)*256 + tid: 4 diag float4
//    loaded once into registers, reused 2x each. Full unroll -> (k&3) is
//    compile-time -> diag regs never spill to scratch.

typedef float f32x4 __attribute__((ext_vector_type(4)));

#define SIZE4 1024                  // 4096 / 4 columns in float4 units
#define N4 8388608                  // 8192 * 4096 / 4 total float4
#define TPB 256
#define PER_THREAD 8
#define CHUNK (TPB * PER_THREAD)    // 2048 float4 = 32 KB, per block
#define BLOCKS (N4 / CHUNK)         // 4096 blocks, exact cover

__global__ __launch_bounds__(TPB) void diag_scale_kernel(
    const f32x4* __restrict__ x,
    const f32x4* __restrict__ d,
    f32x4* __restrict__ out)
{
    const int tid  = threadIdx.x;
    const int base = blockIdx.x * CHUNK;          // multiple of 2048 (≡0 mod 1024)

    // 4 distinct diag vectors for this thread: col = j*256 + tid, j = 0..3
    f32x4 dv0 = d[0 * TPB + tid];
    f32x4 dv1 = d[1 * TPB + tid];
    f32x4 dv2 = d[2 * TPB + tid];
    f32x4 dv3 = d[3 * TPB + tid];

    #pragma unroll
    for (int k = 0; k < PER_THREAD; ++k) {
        const int i = base + k * TPB + tid;       // contiguous 4 KB steps
        const f32x4 xv = x[i];
        const f32x4 dv = (k & 3) == 0 ? dv0
                       : (k & 3) == 1 ? dv1
                       : (k & 3) == 2 ? dv2
                                      : dv3;      // compile-time after unroll
        out[i] = xv * dv;
    }
}

extern "C" void kernel_launch(void* const* d_in, const int* in_sizes, int n_in,
                              void* d_out, int out_size, void* d_ws, size_t ws_size,
                              hipStream_t stream)
{
    const f32x4* x = (const f32x4*)d_in[0];   // (8192, 4096) fp32
    const f32x4* d = (const f32x4*)d_in[1];   // (4096,) fp32
    f32x4* out = (f32x4*)d_out;               // (8192, 4096) fp32

    diag_scale_kernel<<<BLOCKS, TPB, 0, stream>>>(x, d, out);
}

// Round 5
// 227.335 us; speedup vs baseline: 1.0741x; 1.0067x over previous
//
#include <hip/hip_runtime.h>

// out[b, c] = x[b, c] * diag[c]   for x:(8192, 4096) fp32, diag:(4096,) fp32.
// Memory-bound streaming kernel. Ideal traffic = 268.4 MB -> ~43 us at 6.3 TB/s.
//
// Round-5: ONE MATRIX ROW PER BLOCK. History (direct rocprof where available):
//   r0: 1 float4/thread, 32768 blocks          ~77 us (inferred, dur-146)
//   r3: ILP-8, 16MB grid stride                 98 us (L2 set thrash)
//   r4: ILP-8, contiguous 32KB/block            82.5 us
// All cluster at 3.2-3.5 TB/s effective; HBM pins not saturated (2.4 TB/s
// counted) -> latency / vmcnt-chain bound, not BW bound. This round: finer
// blocks (8192 = 32/CU) for better tail + shorter 4-deep load/store chains.
//
//  - Each block = one matrix row: 1024 float4 = 16 KB, contiguous.
//  - Chunk base = blockIdx * 1024 (≡ 0 mod 1024) -> diag col = j*256 + tid,
//    j = 0..3 compile-time -> 4 diag float4 in registers, no masking.
//  - PER_THREAD = 4: thread loads x[base + j*256 + tid], j unrolled.

typedef float f32x4 __attribute__((ext_vector_type(4)));

#define SIZE4 1024                  // 4096 / 4 columns in float4 units
#define N4 8388608                  // 8192 * 4096 / 4 total float4
#define TPB 256
#define PER_THREAD 4
#define CHUNK (TPB * PER_THREAD)    // 1024 float4 = 16 KB = one matrix row
#define BLOCKS (N4 / CHUNK)         // 8192 blocks, exact cover

__global__ __launch_bounds__(TPB) void diag_scale_kernel(
    const f32x4* __restrict__ x,
    const f32x4* __restrict__ d,
    f32x4* __restrict__ out)
{
    const int tid  = threadIdx.x;
    const int base = blockIdx.x * CHUNK;          // row start, ≡ 0 mod 1024

    // This thread's 4 diag vectors: col = j*256 + tid (same for every block)
    const f32x4 dv0 = d[0 * TPB + tid];
    const f32x4 dv1 = d[1 * TPB + tid];
    const f32x4 dv2 = d[2 * TPB + tid];
    const f32x4 dv3 = d[3 * TPB + tid];

    const f32x4 x0 = x[base + 0 * TPB + tid];
    const f32x4 x1 = x[base + 1 * TPB + tid];
    const f32x4 x2 = x[base + 2 * TPB + tid];
    const f32x4 x3 = x[base + 3 * TPB + tid];

    out[base + 0 * TPB + tid] = x0 * dv0;
    out[base + 1 * TPB + tid] = x1 * dv1;
    out[base + 2 * TPB + tid] = x2 * dv2;
    out[base + 3 * TPB + tid] = x3 * dv3;
}

extern "C" void kernel_launch(void* const* d_in, const int* in_sizes, int n_in,
                              void* d_out, int out_size, void* d_ws, size_t ws_size,
                              hipStream_t stream)
{
    const f32x4* x = (const f32x4*)d_in[0];   // (8192, 4096) fp32
    const f32x4* d = (const f32x4*)d_in[1];   // (4096,) fp32
    f32x4* out = (f32x4*)d_out;               // (8192, 4096) fp32

    diag_scale_kernel<<<BLOCKS, TPB, 0, stream>>>(x, d, out);
}

// Round 6
// 226.852 us; speedup vs baseline: 1.0764x; 1.0021x over previous
//
#include <hip/hip_runtime.h>

// out[b, c] = x[b, c] * diag[c]   for x:(8192, 4096) fp32, diag:(4096,) fp32.
// Memory-bound streaming kernel. Ideal traffic = 268.4 MB -> ~43 us at 6.3 TB/s.
//
// Round-6: NONTEMPORAL STORES ONLY (single-variable change vs round 5).
// Evidence:
//  - Kernel plateau 77-83 us across ILP 1/4/8 and 4K-32K blocks -> limiter is
//    not the instruction stream (VALUBusy 1.7%, pins at 2.4 TB/s).
//  - r2 vs r3 (same structure): nt = 89 us, no-nt = 97.7 us -> nt HELPED 9%.
//  - r4 counters: FETCH = 65.6 MB = half of x. L3 (256 MB) holds prev-iter
//    x (134 MB) + out (134 MB), which don't both fit -> our own stores evict
//    our input. nt stores stop out from allocating in L3 -> x fully resident
//    -> FETCH -> ~0, writes stream fill-style (fills do 6.7 TB/s).
// Loads stay REGULAR: x is re-read every iteration; we want it L3-resident.
//
// Structure (unchanged from r5): one matrix row per block, 8192 blocks,
// 4 float4/thread, diag columns j*256+tid held in registers.

typedef float f32x4 __attribute__((ext_vector_type(4)));

#define SIZE4 1024                  // 4096 / 4 columns in float4 units
#define N4 8388608                  // 8192 * 4096 / 4 total float4
#define TPB 256
#define PER_THREAD 4
#define CHUNK (TPB * PER_THREAD)    // 1024 float4 = 16 KB = one matrix row
#define BLOCKS (N4 / CHUNK)         // 8192 blocks, exact cover

__global__ __launch_bounds__(TPB) void diag_scale_kernel(
    const f32x4* __restrict__ x,
    const f32x4* __restrict__ d,
    f32x4* __restrict__ out)
{
    const int tid  = threadIdx.x;
    const int base = blockIdx.x * CHUNK;          // row start, ≡ 0 mod 1024

    // This thread's 4 diag vectors: col = j*256 + tid (same for every block)
    const f32x4 dv0 = d[0 * TPB + tid];
    const f32x4 dv1 = d[1 * TPB + tid];
    const f32x4 dv2 = d[2 * TPB + tid];
    const f32x4 dv3 = d[3 * TPB + tid];

    const f32x4 x0 = x[base + 0 * TPB + tid];
    const f32x4 x1 = x[base + 1 * TPB + tid];
    const f32x4 x2 = x[base + 2 * TPB + tid];
    const f32x4 x3 = x[base + 3 * TPB + tid];

    __builtin_nontemporal_store(x0 * dv0, &out[base + 0 * TPB + tid]);
    __builtin_nontemporal_store(x1 * dv1, &out[base + 1 * TPB + tid]);
    __builtin_nontemporal_store(x2 * dv2, &out[base + 2 * TPB + tid]);
    __builtin_nontemporal_store(x3 * dv3, &out[base + 3 * TPB + tid]);
}

extern "C" void kernel_launch(void* const* d_in, const int* in_sizes, int n_in,
                              void* d_out, int out_size, void* d_ws, size_t ws_size,
                              hipStream_t stream)
{
    const f32x4* x = (const f32x4*)d_in[0];   // (8192, 4096) fp32
    const f32x4* d = (const f32x4*)d_in[1];   // (4096,) fp32
    f32x4* out = (f32x4*)d_out;               // (8192, 4096) fp32

    diag_scale_kernel<<<BLOCKS, TPB, 0, stream>>>(x, d, out);
}